// Round 1
// baseline (4086.425 us; speedup 1.0000x reference)
//
#include <hip/hip_runtime.h>
#include <cstdint>
#include <cstddef>

// ---------------------------------------------------------------------------
// 2-layer GCN (PyG GCNConv semantics) on MI355X, all fp32.
//   deg[i]  = #in-edges(dst==i) + 1 ;  dinv = rsqrt(deg)
//   h   = relu( scatter_dst(coef * (XW1)[src]) + (XW1)*dinv^2 + b1 )
//   out = relu( scatter_dst(coef * (hW2)[src]) + (hW2)*dinv^2 + b2 )
//   coef = dinv[src]*dinv[dst]
// ---------------------------------------------------------------------------

__global__ __launch_bounds__(256) void k_deg(const int* __restrict__ dst,
                                             float* __restrict__ deg, int E) {
  int i = blockIdx.x * 256 + threadIdx.x;
  const int stride = gridDim.x * 256;
  for (; i < E; i += stride) atomicAdd(&deg[dst[i]], 1.0f);
}

__global__ __launch_bounds__(256) void k_dinv(float* __restrict__ deg, int N) {
  int i = blockIdx.x * 256 + threadIdx.x;
  if (i < N) deg[i] = rsqrtf(deg[i] + 1.0f);  // in-place: deg -> dinv
}

// GEMM: H = X @ W  (X:[N,K], W:[K,COUT] row-major), epilogue also writes
// AGG = H * dinv^2 (self-loop init of the aggregation buffer).
// W staged fully in LDS. 32 rows/tile, 2 rows x CPT cols per thread.
template <int K, int COUT>
__global__ __launch_bounds__(256) void k_gemm_selfloop(
    const float* __restrict__ X, const float* __restrict__ W,
    const float* __restrict__ dinv, float* __restrict__ H,
    float* __restrict__ AGG, int N) {
  __shared__ float Ws[K * COUT];  // 64 KB (COUT=128) or 32 KB (COUT=64)
  for (int idx = threadIdx.x; idx < (K * COUT) / 4; idx += 256)
    reinterpret_cast<float4*>(Ws)[idx] = reinterpret_cast<const float4*>(W)[idx];
  __syncthreads();

  constexpr int ROWS = 32;         // rows per tile
  constexpr int TPR  = 16;         // threads per row
  constexpr int CPT  = COUT / TPR; // cols per thread (8 or 4)
  const int rg = threadIdx.x / TPR;  // 0..15
  const int cg = threadIdx.x % TPR;  // 0..15
  const int c0 = cg * CPT;
  const int ntiles = (N + ROWS - 1) / ROWS;

  for (int tile = blockIdx.x; tile < ntiles; tile += gridDim.x) {
    const int row0 = tile * ROWS + rg;       // rows row0 and row0+16
    const bool ok0 = row0 < N;
    const bool ok1 = (row0 + 16) < N;
    const float* xr0 = X + (size_t)row0 * K;
    const float* xr1 = xr0 + (size_t)16 * K;

    float acc0[CPT], acc1[CPT];
#pragma unroll
    for (int j = 0; j < CPT; ++j) { acc0[j] = 0.f; acc1[j] = 0.f; }

    for (int k4 = 0; k4 < K; k4 += 4) {
      float4 xv0 = ok0 ? *reinterpret_cast<const float4*>(xr0 + k4)
                       : float4{0.f, 0.f, 0.f, 0.f};
      float4 xv1 = ok1 ? *reinterpret_cast<const float4*>(xr1 + k4)
                       : float4{0.f, 0.f, 0.f, 0.f};
#pragma unroll
      for (int kk = 0; kk < 4; ++kk) {
        const float x0 = (&xv0.x)[kk];
        const float x1 = (&xv1.x)[kk];
        const float* wr = &Ws[(k4 + kk) * COUT + c0];
#pragma unroll
        for (int j = 0; j < CPT; ++j) {
          const float wv = wr[j];
          acc0[j] = fmaf(x0, wv, acc0[j]);
          acc1[j] = fmaf(x1, wv, acc1[j]);
        }
      }
    }

#pragma unroll
    for (int q = 0; q < 2; ++q) {
      const int row = row0 + q * 16;
      if (row >= N) continue;
      const float* accp = q ? acc1 : acc0;
      const float di = dinv[row];
      const float d2 = di * di;
      float* hp = H + (size_t)row * COUT + c0;
      float* ap = AGG + (size_t)row * COUT + c0;
#pragma unroll
      for (int j = 0; j < CPT; j += 4) {
        float4 v;
        v.x = accp[j]; v.y = accp[j + 1]; v.z = accp[j + 2]; v.w = accp[j + 3];
        *reinterpret_cast<float4*>(hp + j) = v;
        float4 a;
        a.x = v.x * d2; a.y = v.y * d2; a.z = v.z * d2; a.w = v.w * d2;
        *reinterpret_cast<float4*>(ap + j) = a;
      }
    }
  }
}

// Edge aggregation, 128 channels: one wave per edge, lane covers 2 channels
// (float2 gather = 512 B coalesced per edge), atomicAdd scatter to AGG[dst].
__global__ __launch_bounds__(256) void k_agg_c128(
    const float* __restrict__ H, const int* __restrict__ src,
    const int* __restrict__ dst, const float* __restrict__ dinv,
    float* __restrict__ AGG, int E) {
  const int lane = threadIdx.x & 63;
  int w = (blockIdx.x * 256 + threadIdx.x) >> 6;
  const int nw = (gridDim.x * 256) >> 6;
  for (int e = w; e < E; e += nw) {
    const int s = src[e];
    const int d = dst[e];
    const float coef = dinv[s] * dinv[d];
    const float2 h2 =
        *reinterpret_cast<const float2*>(H + (size_t)s * 128 + lane * 2);
    float* a = AGG + (size_t)d * 128 + lane * 2;
    atomicAdd(a, coef * h2.x);
    atomicAdd(a + 1, coef * h2.y);
  }
}

// Edge aggregation, 64 channels: one wave per edge, lane covers 1 channel.
__global__ __launch_bounds__(256) void k_agg_c64(
    const float* __restrict__ H, const int* __restrict__ src,
    const int* __restrict__ dst, const float* __restrict__ dinv,
    float* __restrict__ AGG, int E) {
  const int lane = threadIdx.x & 63;
  int w = (blockIdx.x * 256 + threadIdx.x) >> 6;
  const int nw = (gridDim.x * 256) >> 6;
  for (int e = w; e < E; e += nw) {
    const int s = src[e];
    const int d = dst[e];
    const float coef = dinv[s] * dinv[d];
    const float hv = H[(size_t)s * 64 + lane];
    atomicAdd(AGG + (size_t)d * 64 + lane, coef * hv);
  }
}

// out = relu(A + bias[c]), vectorized float4. In-place safe (elementwise).
template <int C>
__global__ __launch_bounds__(256) void k_bias_relu(
    const float* __restrict__ A, const float* __restrict__ bias,
    float* __restrict__ out, long total4) {
  long i = (long)blockIdx.x * 256 + threadIdx.x;
  const long stride = (long)gridDim.x * 256;
  for (; i < total4; i += stride) {
    float4 v = reinterpret_cast<const float4*>(A)[i];
    const int c = (int)(i & (C / 4 - 1)) * 4;
    const float4 b = *reinterpret_cast<const float4*>(bias + c);
    v.x = fmaxf(v.x + b.x, 0.f);
    v.y = fmaxf(v.y + b.y, 0.f);
    v.z = fmaxf(v.z + b.z, 0.f);
    v.w = fmaxf(v.w + b.w, 0.f);
    reinterpret_cast<float4*>(out)[i] = v;
  }
}

extern "C" void kernel_launch(void* const* d_in, const int* in_sizes, int n_in,
                              void* d_out, int out_size, void* d_ws,
                              size_t ws_size, hipStream_t stream) {
  const float* x  = (const float*)d_in[0];
  const int*   ei = (const int*)d_in[1];
  const float* W1 = (const float*)d_in[2];
  const float* b1 = (const float*)d_in[3];
  const float* W2 = (const float*)d_in[4];
  const float* b2 = (const float*)d_in[5];

  const int IN  = 128;
  const int n   = in_sizes[0] / IN;        // 100000
  const int E   = in_sizes[1] / 2;         // 3200000
  const int HID = in_sizes[2] / IN;        // 128
  const int OUT = in_sizes[4] / HID;       // 64
  const int* srcv = ei;
  const int* dstv = ei + E;
  float* out = (float*)d_out;

  // Workspace partition: dinv (0.4MB) + bufA (51.2MB) + bufB (51.2MB).
  // bufB is reused for layer-2 h (dead agg1 space); layer-2 agg lands in d_out.
  char* p = (char*)d_ws;
  auto take = [&](size_t bytes) {
    char* r = p;
    p += (bytes + 255) & ~(size_t)255;
    return r;
  };
  float* dinv = (float*)take((size_t)n * 4);
  float* bufA = (float*)take((size_t)n * HID * 4);  // h1, then h1' (post-relu)
  float* bufB = (float*)take((size_t)n * HID * 4);  // agg1, then h2

  // --- degree / dinv ---
  hipMemsetAsync(dinv, 0, (size_t)n * 4, stream);
  k_deg<<<1024, 256, 0, stream>>>(dstv, dinv, E);
  k_dinv<<<(n + 255) / 256, 256, 0, stream>>>(dinv, n);

  // --- layer 1 ---
  k_gemm_selfloop<128, 128><<<2048, 256, 0, stream>>>(x, W1, dinv, bufA, bufB, n);
  k_agg_c128<<<4096, 256, 0, stream>>>(bufA, srcv, dstv, dinv, bufB, E);
  k_bias_relu<128><<<4096, 256, 0, stream>>>(bufB, b1, bufA, (long)n * (HID / 4));

  // --- layer 2 ---
  k_gemm_selfloop<128, 64><<<2048, 256, 0, stream>>>(bufA, W2, dinv, bufB, out, n);
  k_agg_c64<<<4096, 256, 0, stream>>>(bufB, srcv, dstv, dinv, out, E);
  k_bias_relu<64><<<2048, 256, 0, stream>>>(out, b2, out, (long)n * (OUT / 4));
}

// Round 3
// 2393.334 us; speedup vs baseline: 1.7074x; 1.7074x over previous
//
#include <hip/hip_runtime.h>
#include <cstdint>
#include <cstddef>

// ---------------------------------------------------------------------------
// 2-layer GCN (PyG GCNConv semantics) on MI355X, all fp32.
// Round 2 (resubmit after infra failure): scatter-atomics -> CSR gather (one
// wave per dst node), fused self-loop + bias + relu epilogue. Layer 1 split
// into two 64-col halves so total workspace stays ~91 MB.
// ---------------------------------------------------------------------------

__global__ __launch_bounds__(256) void k_count(const int* __restrict__ dst,
                                               int* __restrict__ counts, int E) {
  int i = blockIdx.x * 256 + threadIdx.x;
  const int stride = gridDim.x * 256;
  for (; i < E; i += stride) atomicAdd(&counts[dst[i]], 1);
}

__global__ __launch_bounds__(256) void k_dinv(const int* __restrict__ counts,
                                              float* __restrict__ dinv, int N) {
  int i = blockIdx.x * 256 + threadIdx.x;
  if (i < N) dinv[i] = rsqrtf((float)counts[i] + 1.0f);
}

// ---- hierarchical exclusive scan over counts[n] -> offsets[n] (+ blocksums)
// chunk = 1024 items per block (256 threads x 4)
__global__ __launch_bounds__(256) void k_scan1(const int* __restrict__ counts,
                                               int* __restrict__ offsets,
                                               int* __restrict__ blocksums, int n) {
  __shared__ int ts[256];
  const int b = blockIdx.x;
  const int i0 = b * 1024 + threadIdx.x * 4;
  int v[4];
  int local = 0;
#pragma unroll
  for (int j = 0; j < 4; ++j) {
    const int i = i0 + j;
    v[j] = (i < n) ? counts[i] : 0;
    local += v[j];
  }
  ts[threadIdx.x] = local;
  __syncthreads();
  for (int off = 1; off < 256; off <<= 1) {
    const int t = (threadIdx.x >= off) ? ts[threadIdx.x - off] : 0;
    __syncthreads();
    ts[threadIdx.x] += t;
    __syncthreads();
  }
  const int excl = ts[threadIdx.x] - local;
  if (threadIdx.x == 255) blocksums[b] = ts[255];
  int run = excl;
#pragma unroll
  for (int j = 0; j < 4; ++j) {
    const int i = i0 + j;
    if (i < n) offsets[i] = run;
    run += v[j];
  }
}

__global__ __launch_bounds__(256) void k_scan2(int* __restrict__ blocksums, int nb) {
  __shared__ int ts[256];
  if (nb <= 256) {
    const int t = threadIdx.x;
    const int s = (t < nb) ? blocksums[t] : 0;
    ts[t] = s;
    __syncthreads();
    for (int off = 1; off < 256; off <<= 1) {
      const int u = (t >= off) ? ts[t - off] : 0;
      __syncthreads();
      ts[t] += u;
      __syncthreads();
    }
    if (t < nb) blocksums[t] = ts[t] - s;  // exclusive
  } else if (threadIdx.x == 0) {
    int run = 0;
    for (int i = 0; i < nb; ++i) {
      const int s = blocksums[i];
      blocksums[i] = run;
      run += s;
    }
  }
}

__global__ __launch_bounds__(256) void k_scan3(int* __restrict__ offsets,
                                               const int* __restrict__ blocksums,
                                               int* __restrict__ cursor, int n, int E) {
  int i = blockIdx.x * 256 + threadIdx.x;
  const int stride = gridDim.x * 256;
  for (; i < n; i += stride) {
    const int o = offsets[i] + blocksums[i >> 10];
    offsets[i] = o;
    cursor[i] = o;
    if (i == 0) offsets[n] = E;
  }
}

__global__ __launch_bounds__(256) void k_fill(const int* __restrict__ src,
                                              const int* __restrict__ dst,
                                              int* __restrict__ cursor,
                                              int* __restrict__ csr_src, int E) {
  int e = blockIdx.x * 256 + threadIdx.x;
  const int stride = gridDim.x * 256;
  for (; e < E; e += stride) {
    const int d = dst[e];
    const int pos = atomicAdd(&cursor[d], 1);
    csr_src[pos] = src[e];
  }
}

// GEMM: H[N,COLS] = X[N,K] @ W[:, c0:c0+COLS]  (W row-major, leading dim ldw).
// W tile staged in LDS (K*COLS*4 bytes = 32 KB for COLS=64).
template <int K, int COLS>
__global__ __launch_bounds__(256) void k_gemm(const float* __restrict__ X,
                                              const float* __restrict__ W, int ldw,
                                              int c0, float* __restrict__ H, int N) {
  __shared__ float Ws[K * COLS];
  for (int f = threadIdx.x; f < (K * COLS) / 4; f += 256) {
    const int k = f / (COLS / 4);
    const int j4 = f % (COLS / 4);
    reinterpret_cast<float4*>(Ws)[f] =
        reinterpret_cast<const float4*>(W + (size_t)k * ldw + c0)[j4];
  }
  __syncthreads();

  constexpr int ROWS = 32;
  constexpr int TPR = 16;
  constexpr int CPT = COLS / TPR;  // 4
  const int rg = threadIdx.x / TPR;
  const int cg = threadIdx.x % TPR;
  const int cc = cg * CPT;
  const int ntiles = (N + ROWS - 1) / ROWS;

  for (int tile = blockIdx.x; tile < ntiles; tile += gridDim.x) {
    const int row0 = tile * ROWS + rg;  // rows row0, row0+16
    const bool ok0 = row0 < N;
    const bool ok1 = (row0 + 16) < N;
    const float* xr0 = X + (size_t)row0 * K;
    const float* xr1 = xr0 + (size_t)16 * K;

    float acc0[CPT], acc1[CPT];
#pragma unroll
    for (int j = 0; j < CPT; ++j) { acc0[j] = 0.f; acc1[j] = 0.f; }

    for (int k4 = 0; k4 < K; k4 += 4) {
      float4 xv0 = ok0 ? *reinterpret_cast<const float4*>(xr0 + k4)
                       : float4{0.f, 0.f, 0.f, 0.f};
      float4 xv1 = ok1 ? *reinterpret_cast<const float4*>(xr1 + k4)
                       : float4{0.f, 0.f, 0.f, 0.f};
#pragma unroll
      for (int kk = 0; kk < 4; ++kk) {
        const float x0 = (&xv0.x)[kk];
        const float x1 = (&xv1.x)[kk];
        const float* wr = &Ws[(k4 + kk) * COLS + cc];
#pragma unroll
        for (int j = 0; j < CPT; ++j) {
          const float wv = wr[j];
          acc0[j] = fmaf(x0, wv, acc0[j]);
          acc1[j] = fmaf(x1, wv, acc1[j]);
        }
      }
    }

#pragma unroll
    for (int q = 0; q < 2; ++q) {
      const int row = row0 + q * 16;
      if (row >= N) continue;
      const float* accp = q ? acc1 : acc0;
      float4 v;
      v.x = accp[0]; v.y = accp[1]; v.z = accp[2]; v.w = accp[3];
      *reinterpret_cast<float4*>(H + (size_t)row * COLS + cc) = v;
    }
  }
}

// CSR gather-aggregate, fused self-loop + bias + relu.
// One wave per dst node; lane = channel (64 channels). H:[N,64].
// out[i*out_ld + c0 + lane] = relu( H[i]*dinv[i]^2 + sum coef*H[s] + bias[c0+lane] )
__global__ __launch_bounds__(256) void k_gather(const float* __restrict__ H,
                                                const int* __restrict__ offsets,
                                                const int* __restrict__ csr_src,
                                                const float* __restrict__ dinv,
                                                const float* __restrict__ bias,
                                                int c0, float* __restrict__ out,
                                                int out_ld, int N) {
  const int lane = threadIdx.x & 63;
  int w = (blockIdx.x * 256 + threadIdx.x) >> 6;
  const int nw = (gridDim.x * 256) >> 6;
  for (int i = w; i < N; i += nw) {
    const float di = dinv[i];
    float acc = H[(size_t)i * 64 + lane] * di * di;
    const int beg = offsets[i];
    const int end = offsets[i + 1];
    int idx = beg;
    for (; idx + 1 < end; idx += 2) {
      const int s0 = csr_src[idx];
      const int s1 = csr_src[idx + 1];
      const float h0 = H[(size_t)s0 * 64 + lane];
      const float h1 = H[(size_t)s1 * 64 + lane];
      const float cf0 = dinv[s0] * di;
      const float cf1 = dinv[s1] * di;
      acc = fmaf(cf0, h0, acc);
      acc = fmaf(cf1, h1, acc);
    }
    if (idx < end) {
      const int s0 = csr_src[idx];
      acc = fmaf(dinv[s0] * di, H[(size_t)s0 * 64 + lane], acc);
    }
    const float v = acc + bias[c0 + lane];
    out[(size_t)i * out_ld + c0 + lane] = fmaxf(v, 0.f);
  }
}

extern "C" void kernel_launch(void* const* d_in, const int* in_sizes, int n_in,
                              void* d_out, int out_size, void* d_ws,
                              size_t ws_size, hipStream_t stream) {
  const float* x  = (const float*)d_in[0];
  const int*   ei = (const int*)d_in[1];
  const float* W1 = (const float*)d_in[2];
  const float* b1 = (const float*)d_in[3];
  const float* W2 = (const float*)d_in[4];
  const float* b2 = (const float*)d_in[5];

  const int IN  = 128;
  const int n   = in_sizes[0] / IN;   // 100000
  const int E   = in_sizes[1] / 2;    // 3200000
  const int HID = in_sizes[2] / IN;   // 128
  const int* srcv = ei;
  const int* dstv = ei + E;
  float* out = (float*)d_out;

  const int NB = (n + 1023) / 1024;   // scan blocks (98)

  // Workspace: ~91 MB total.
  char* p = (char*)d_ws;
  auto take = [&](size_t bytes) {
    char* r = p;
    p += (bytes + 255) & ~(size_t)255;
    return r;
  };
  float* dinv      = (float*)take((size_t)n * 4);
  int*   counts    = (int*)take((size_t)n * 4);
  int*   offsets   = (int*)take((size_t)(n + 1) * 4);
  int*   cursor    = (int*)take((size_t)n * 4);
  int*   blocksums = (int*)take((size_t)((NB + 255) & ~255) * 4);
  int*   csr_src   = (int*)take((size_t)E * 4);           // 12.8 MB
  float* bufH      = (float*)take((size_t)n * 64 * 4);    // 25.6 MB (H halves, then H2)
  float* bufHp     = (float*)take((size_t)n * HID * 4);   // 51.2 MB (h' = relu layer-1 out)

  // --- degree + CSR build ---
  hipMemsetAsync(counts, 0, (size_t)n * 4, stream);
  k_count<<<1024, 256, 0, stream>>>(dstv, counts, E);
  k_dinv<<<(n + 255) / 256, 256, 0, stream>>>(counts, dinv, n);
  k_scan1<<<NB, 256, 0, stream>>>(counts, offsets, blocksums, n);
  k_scan2<<<1, 256, 0, stream>>>(blocksums, NB);
  k_scan3<<<(n + 255) / 256, 256, 0, stream>>>(offsets, blocksums, cursor, n, E);
  k_fill<<<2048, 256, 0, stream>>>(srcv, dstv, cursor, csr_src, E);

  // --- layer 1 (two 64-column halves), fused agg+bias+relu -> bufHp[N,128] ---
  k_gemm<128, 64><<<2048, 256, 0, stream>>>(x, W1, HID, 0, bufH, n);
  k_gather<<<25000, 256, 0, stream>>>(bufH, offsets, csr_src, dinv, b1, 0,
                                      bufHp, HID, n);
  k_gemm<128, 64><<<2048, 256, 0, stream>>>(x, W1, HID, 64, bufH, n);
  k_gather<<<25000, 256, 0, stream>>>(bufH, offsets, csr_src, dinv, b1, 64,
                                      bufHp, HID, n);

  // --- layer 2: H2 = h' @ W2 -> bufH ; gather -> d_out ---
  k_gemm<128, 64><<<2048, 256, 0, stream>>>(bufHp, W2, 64, 0, bufH, n);
  k_gather<<<25000, 256, 0, stream>>>(bufH, offsets, csr_src, dinv, b2, 0,
                                      out, 64, n);
}

// Round 6
// 1044.823 us; speedup vs baseline: 3.9111x; 2.2907x over previous
//
#include <hip/hip_runtime.h>
#include <cstdint>
#include <cstddef>

// ---------------------------------------------------------------------------
// 2-layer GCN (PyG GCNConv semantics) on MI355X, all fp32.
// Round 3 (2nd resubmit after repeated infra failures): fix GEMM 17x HBM
// over-fetch -> LDS-tiled 64x64 GEMM with transposed+swizzled X tile, 4x4
// register tiles. CSR gather unchanged.
// ---------------------------------------------------------------------------

__global__ __launch_bounds__(256) void k_count(const int* __restrict__ dst,
                                               int* __restrict__ counts, int E) {
  int i = blockIdx.x * 256 + threadIdx.x;
  const int stride = gridDim.x * 256;
  for (; i < E; i += stride) atomicAdd(&counts[dst[i]], 1);
}

__global__ __launch_bounds__(256) void k_dinv(const int* __restrict__ counts,
                                              float* __restrict__ dinv, int N) {
  int i = blockIdx.x * 256 + threadIdx.x;
  if (i < N) dinv[i] = rsqrtf((float)counts[i] + 1.0f);
}

// ---- hierarchical exclusive scan over counts[n] -> offsets[n] (+ blocksums)
__global__ __launch_bounds__(256) void k_scan1(const int* __restrict__ counts,
                                               int* __restrict__ offsets,
                                               int* __restrict__ blocksums, int n) {
  __shared__ int ts[256];
  const int b = blockIdx.x;
  const int i0 = b * 1024 + threadIdx.x * 4;
  int v[4];
  int local = 0;
#pragma unroll
  for (int j = 0; j < 4; ++j) {
    const int i = i0 + j;
    v[j] = (i < n) ? counts[i] : 0;
    local += v[j];
  }
  ts[threadIdx.x] = local;
  __syncthreads();
  for (int off = 1; off < 256; off <<= 1) {
    const int t = (threadIdx.x >= off) ? ts[threadIdx.x - off] : 0;
    __syncthreads();
    ts[threadIdx.x] += t;
    __syncthreads();
  }
  const int excl = ts[threadIdx.x] - local;
  if (threadIdx.x == 255) blocksums[b] = ts[255];
  int run = excl;
#pragma unroll
  for (int j = 0; j < 4; ++j) {
    const int i = i0 + j;
    if (i < n) offsets[i] = run;
    run += v[j];
  }
}

__global__ __launch_bounds__(256) void k_scan2(int* __restrict__ blocksums, int nb) {
  __shared__ int ts[256];
  if (nb <= 256) {
    const int t = threadIdx.x;
    const int s = (t < nb) ? blocksums[t] : 0;
    ts[t] = s;
    __syncthreads();
    for (int off = 1; off < 256; off <<= 1) {
      const int u = (t >= off) ? ts[t - off] : 0;
      __syncthreads();
      ts[t] += u;
      __syncthreads();
    }
    if (t < nb) blocksums[t] = ts[t] - s;  // exclusive
  } else if (threadIdx.x == 0) {
    int run = 0;
    for (int i = 0; i < nb; ++i) {
      const int s = blocksums[i];
      blocksums[i] = run;
      run += s;
    }
  }
}

__global__ __launch_bounds__(256) void k_scan3(int* __restrict__ offsets,
                                               const int* __restrict__ blocksums,
                                               int* __restrict__ cursor, int n, int E) {
  int i = blockIdx.x * 256 + threadIdx.x;
  const int stride = gridDim.x * 256;
  for (; i < n; i += stride) {
    const int o = offsets[i] + blocksums[i >> 10];
    offsets[i] = o;
    cursor[i] = o;
    if (i == 0) offsets[n] = E;
  }
}

__global__ __launch_bounds__(256) void k_fill(const int* __restrict__ src,
                                              const int* __restrict__ dst,
                                              int* __restrict__ cursor,
                                              int* __restrict__ csr_src, int E) {
  int e = blockIdx.x * 256 + threadIdx.x;
  const int stride = gridDim.x * 256;
  for (; e < E; e += stride) {
    const int d = dst[e];
    const int pos = atomicAdd(&cursor[d], 1);
    csr_src[pos] = src[e];
  }
}

// ---------------------------------------------------------------------------
// LDS-tiled GEMM: H[N,COLS] = X[N,K] @ W[:, c0:c0+COLS] (W row-major, ld=ldw).
// Block tile 64 rows x COLS(=64) cols. X tile stored TRANSPOSED in LDS
// (Xs[k][r], stride 64 floats) with XOR-swizzled float4 granules:
//   granule a = r>>2 stored at position a ^ (k4 & 15)  (k4 = k>>2)
// -> staging writes <=4-way bank conflict, compute reads 2-way/broadcast.
// Thread (tid): rows r0 = (tid>>4)*4, cols cc = (tid&15)*4; 4x4 outer product.
// LDS = 32 KB Xs + 32 KB Ws = 64 KB -> 2 blocks/CU.
// ---------------------------------------------------------------------------
template <int K, int COLS>
__global__ __launch_bounds__(256) void k_gemm(const float* __restrict__ X,
                                              const float* __restrict__ W, int ldw,
                                              int c0, float* __restrict__ H, int N) {
  constexpr int BM = 64;
  __shared__ float Xs[K * BM];    // transposed + swizzled
  __shared__ float Ws[K * COLS];  // [k][c] linear
  const int tid = threadIdx.x;

  // stage W: consecutive tids -> consecutive float4s (coalesced, no conflicts)
  for (int f = tid; f < (K * COLS) / 4; f += 256) {
    const int k = f / (COLS / 4);
    const int j4 = f % (COLS / 4);
    reinterpret_cast<float4*>(Ws)[f] =
        *reinterpret_cast<const float4*>(W + (size_t)k * ldw + c0 + j4 * 4);
  }

  const int row0 = blockIdx.x * BM;
  // stage X: f -> (r = f/32, k4 = f%32); lanes sweep k4 -> 512B coalesced reads.
  for (int f = tid; f < BM * (K / 4); f += 256) {
    const int r = f / (K / 4);
    const int k4 = f % (K / 4);
    const int row = row0 + r;
    float4 xv = (row < N)
                    ? *reinterpret_cast<const float4*>(X + (size_t)row * K + k4 * 4)
                    : float4{0.f, 0.f, 0.f, 0.f};
    const int cs = ((((r >> 2) ^ (k4 & 15)) << 2) | (r & 3));
#pragma unroll
    for (int j = 0; j < 4; ++j) Xs[(k4 * 4 + j) * BM + cs] = (&xv.x)[j];
  }
  __syncthreads();

  const int r0 = (tid >> 4) * 4;  // row group (store-coalescing friendly)
  const int cc = (tid & 15) * 4;  // col group
  const int a = r0 >> 2;
  float acc[4][4] = {};

  for (int k4 = 0; k4 < K / 4; ++k4) {
    const int xbase = (k4 * 4) * BM + ((a ^ (k4 & 15)) << 2);
    const int wbase = (k4 * 4) * COLS + cc;
#pragma unroll
    for (int j = 0; j < 4; ++j) {
      const float4 xv = *reinterpret_cast<const float4*>(&Xs[xbase + j * BM]);
      const float4 wv = *reinterpret_cast<const float4*>(&Ws[wbase + j * COLS]);
#pragma unroll
      for (int i = 0; i < 4; ++i) {
        const float xi = (&xv.x)[i];
        acc[i][0] = fmaf(xi, wv.x, acc[i][0]);
        acc[i][1] = fmaf(xi, wv.y, acc[i][1]);
        acc[i][2] = fmaf(xi, wv.z, acc[i][2]);
        acc[i][3] = fmaf(xi, wv.w, acc[i][3]);
      }
    }
  }

#pragma unroll
  for (int i = 0; i < 4; ++i) {
    const int row = row0 + r0 + i;
    if (row < N) {
      float4 v;
      v.x = acc[i][0]; v.y = acc[i][1]; v.z = acc[i][2]; v.w = acc[i][3];
      *reinterpret_cast<float4*>(H + (size_t)row * COLS + cc) = v;
    }
  }
}

// CSR gather-aggregate, fused self-loop + bias + relu.
// One wave per dst node; lane = channel (64 channels). H:[N,64].
__global__ __launch_bounds__(256) void k_gather(const float* __restrict__ H,
                                                const int* __restrict__ offsets,
                                                const int* __restrict__ csr_src,
                                                const float* __restrict__ dinv,
                                                const float* __restrict__ bias,
                                                int c0, float* __restrict__ out,
                                                int out_ld, int N) {
  const int lane = threadIdx.x & 63;
  int w = (blockIdx.x * 256 + threadIdx.x) >> 6;
  const int nw = (gridDim.x * 256) >> 6;
  for (int i = w; i < N; i += nw) {
    const float di = dinv[i];
    float acc = H[(size_t)i * 64 + lane] * di * di;
    const int beg = offsets[i];
    const int end = offsets[i + 1];
    int idx = beg;
    for (; idx + 1 < end; idx += 2) {
      const int s0 = csr_src[idx];
      const int s1 = csr_src[idx + 1];
      const float h0 = H[(size_t)s0 * 64 + lane];
      const float h1 = H[(size_t)s1 * 64 + lane];
      const float cf0 = dinv[s0] * di;
      const float cf1 = dinv[s1] * di;
      acc = fmaf(cf0, h0, acc);
      acc = fmaf(cf1, h1, acc);
    }
    if (idx < end) {
      const int s0 = csr_src[idx];
      acc = fmaf(dinv[s0] * di, H[(size_t)s0 * 64 + lane], acc);
    }
    const float v = acc + bias[c0 + lane];
    out[(size_t)i * out_ld + c0 + lane] = fmaxf(v, 0.f);
  }
}

extern "C" void kernel_launch(void* const* d_in, const int* in_sizes, int n_in,
                              void* d_out, int out_size, void* d_ws,
                              size_t ws_size, hipStream_t stream) {
  const float* x  = (const float*)d_in[0];
  const int*   ei = (const int*)d_in[1];
  const float* W1 = (const float*)d_in[2];
  const float* b1 = (const float*)d_in[3];
  const float* W2 = (const float*)d_in[4];
  const float* b2 = (const float*)d_in[5];

  const int IN  = 128;
  const int n   = in_sizes[0] / IN;   // 100000
  const int E   = in_sizes[1] / 2;    // 3200000
  const int HID = in_sizes[2] / IN;   // 128
  const int* srcv = ei;
  const int* dstv = ei + E;
  float* out = (float*)d_out;

  const int NB = (n + 1023) / 1024;   // scan blocks (98)
  const int NT = (n + 63) / 64;       // gemm tiles (1563)

  // Workspace: ~91 MB total.
  char* p = (char*)d_ws;
  auto take = [&](size_t bytes) {
    char* r = p;
    p += (bytes + 255) & ~(size_t)255;
    return r;
  };
  float* dinv      = (float*)take((size_t)n * 4);
  int*   counts    = (int*)take((size_t)n * 4);
  int*   offsets   = (int*)take((size_t)(n + 1) * 4);
  int*   cursor    = (int*)take((size_t)n * 4);
  int*   blocksums = (int*)take((size_t)((NB + 255) & ~255) * 4);
  int*   csr_src   = (int*)take((size_t)E * 4);           // 12.8 MB
  float* bufH      = (float*)take((size_t)n * 64 * 4);    // 25.6 MB (H halves, then H2)
  float* bufHp     = (float*)take((size_t)n * HID * 4);   // 51.2 MB (h')

  // --- degree + CSR build ---
  hipMemsetAsync(counts, 0, (size_t)n * 4, stream);
  k_count<<<1024, 256, 0, stream>>>(dstv, counts, E);
  k_dinv<<<(n + 255) / 256, 256, 0, stream>>>(counts, dinv, n);
  k_scan1<<<NB, 256, 0, stream>>>(counts, offsets, blocksums, n);
  k_scan2<<<1, 256, 0, stream>>>(blocksums, NB);
  k_scan3<<<(n + 255) / 256, 256, 0, stream>>>(offsets, blocksums, cursor, n, E);
  k_fill<<<2048, 256, 0, stream>>>(srcv, dstv, cursor, csr_src, E);

  // --- layer 1 (two 64-column halves), fused agg+bias+relu -> bufHp[N,128] ---
  k_gemm<128, 64><<<NT, 256, 0, stream>>>(x, W1, HID, 0, bufH, n);
  k_gather<<<25000, 256, 0, stream>>>(bufH, offsets, csr_src, dinv, b1, 0,
                                      bufHp, HID, n);
  k_gemm<128, 64><<<NT, 256, 0, stream>>>(x, W1, HID, 64, bufH, n);
  k_gather<<<25000, 256, 0, stream>>>(bufH, offsets, csr_src, dinv, b1, 64,
                                      bufHp, HID, n);

  // --- layer 2: H2 = h' @ W2 -> bufH ; gather -> d_out ---
  k_gemm<128, 64><<<NT, 256, 0, stream>>>(bufHp, W2, 64, 0, bufH, n);
  k_gather<<<25000, 256, 0, stream>>>(bufH, offsets, csr_src, dinv, b2, 0,
                                      out, 64, n);
}

// Round 7
// 717.573 us; speedup vs baseline: 5.6948x; 1.4561x over previous
//
#include <hip/hip_runtime.h>
#include <hip/hip_fp16.h>
#include <cstdint>
#include <cstddef>

// ---------------------------------------------------------------------------
// 2-layer GCN (PyG GCNConv semantics) on MI355X.
// Round 7: (1) bucketed two-phase CSR fill (kills 196MB scattered write-back),
// (2) fp16 H buffers for gathers (halves gather read traffic), layer-1 gather
// merged to one 128-ch pass. Accumulation stays fp32.
// ---------------------------------------------------------------------------

#define BSHIFT 8  // 256 nodes per bucket

__global__ __launch_bounds__(256) void k_count(const int* __restrict__ dst,
                                               int* __restrict__ counts, int E) {
  int i = blockIdx.x * 256 + threadIdx.x;
  const int stride = gridDim.x * 256;
  for (; i < E; i += stride) atomicAdd(&counts[dst[i]], 1);
}

__global__ __launch_bounds__(256) void k_dinv(const int* __restrict__ counts,
                                              float* __restrict__ dinv, int N) {
  int i = blockIdx.x * 256 + threadIdx.x;
  if (i < N) dinv[i] = rsqrtf((float)counts[i] + 1.0f);
}

// ---- hierarchical exclusive scan over counts[n] -> offsets[n] (+ blocksums)
__global__ __launch_bounds__(256) void k_scan1(const int* __restrict__ counts,
                                               int* __restrict__ offsets,
                                               int* __restrict__ blocksums, int n) {
  __shared__ int ts[256];
  const int b = blockIdx.x;
  const int i0 = b * 1024 + threadIdx.x * 4;
  int v[4];
  int local = 0;
#pragma unroll
  for (int j = 0; j < 4; ++j) {
    const int i = i0 + j;
    v[j] = (i < n) ? counts[i] : 0;
    local += v[j];
  }
  ts[threadIdx.x] = local;
  __syncthreads();
  for (int off = 1; off < 256; off <<= 1) {
    const int t = (threadIdx.x >= off) ? ts[threadIdx.x - off] : 0;
    __syncthreads();
    ts[threadIdx.x] += t;
    __syncthreads();
  }
  const int excl = ts[threadIdx.x] - local;
  if (threadIdx.x == 255) blocksums[b] = ts[255];
  int run = excl;
#pragma unroll
  for (int j = 0; j < 4; ++j) {
    const int i = i0 + j;
    if (i < n) offsets[i] = run;
    run += v[j];
  }
}

__global__ __launch_bounds__(256) void k_scan2(int* __restrict__ blocksums, int nb) {
  __shared__ int ts[256];
  if (nb <= 256) {
    const int t = threadIdx.x;
    const int s = (t < nb) ? blocksums[t] : 0;
    ts[t] = s;
    __syncthreads();
    for (int off = 1; off < 256; off <<= 1) {
      const int u = (t >= off) ? ts[t - off] : 0;
      __syncthreads();
      ts[t] += u;
      __syncthreads();
    }
    if (t < nb) blocksums[t] = ts[t] - s;  // exclusive
  } else if (threadIdx.x == 0) {
    int run = 0;
    for (int i = 0; i < nb; ++i) {
      const int s = blocksums[i];
      blocksums[i] = run;
      run += s;
    }
  }
}

__global__ __launch_bounds__(256) void k_scan3(int* __restrict__ offsets,
                                               const int* __restrict__ blocksums,
                                               int n, int E) {
  int i = blockIdx.x * 256 + threadIdx.x;
  const int stride = gridDim.x * 256;
  for (; i < n; i += stride) {
    offsets[i] = offsets[i] + blocksums[i >> 10];
    if (i == 0) offsets[n] = E;
  }
}

// bucket cursor init: bktcur[b] = offsets[b<<BSHIFT]
__global__ __launch_bounds__(256) void k_bktinit(const int* __restrict__ offsets,
                                                 int* __restrict__ bktcur, int nbkt) {
  int b = blockIdx.x * 256 + threadIdx.x;
  if (b < nbkt) bktcur[b] = offsets[b << BSHIFT];
}

// Pass B: partition edges by dst-bucket into part[] (packed (src<<8)|dst_low).
// Per-block LDS histogram -> one global reservation per bucket -> chunked writes.
__global__ __launch_bounds__(256) void k_part(const int* __restrict__ src,
                                              const int* __restrict__ dst,
                                              int* __restrict__ bktcur,
                                              int* __restrict__ part, int E,
                                              int nbkt) {
  __shared__ int hist[512];
  const int tid = threadIdx.x;
  const int e0 = blockIdx.x * 4096;
  for (int b = tid; b < nbkt; b += 256) hist[b] = 0;
  __syncthreads();
#pragma unroll
  for (int j = 0; j < 16; ++j) {
    const int e = e0 + j * 256 + tid;
    if (e < E) atomicAdd(&hist[dst[e] >> BSHIFT], 1);
  }
  __syncthreads();
  for (int b = tid; b < nbkt; b += 256) {
    const int c = hist[b];
    hist[b] = c ? atomicAdd(&bktcur[b], c) : 0;  // hist becomes running cursor
  }
  __syncthreads();
#pragma unroll
  for (int j = 0; j < 16; ++j) {
    const int e = e0 + j * 256 + tid;
    if (e < E) {
      const int d = dst[e];
      const int pos = atomicAdd(&hist[d >> BSHIFT], 1);
      part[pos] = (src[e] << BSHIFT) | (d & ((1 << BSHIFT) - 1));
    }
  }
}

// Pass C: within each bucket, scatter src to final CSR slots. Cursors in LDS;
// csr writes confined to a ~32KB window -> L2-local.
__global__ __launch_bounds__(256) void k_csr(const int* __restrict__ part,
                                             const int* __restrict__ offsets,
                                             int* __restrict__ csr_src, int n) {
  __shared__ int cur[256];
  const int b = blockIdx.x;
  const int node0 = b << BSHIFT;
  const int node1 = min(n, node0 + 256);
  const int tid = threadIdx.x;
  if (node0 + tid < node1) cur[tid] = offsets[node0 + tid];
  __syncthreads();
  const int e1 = offsets[node1];
  for (int e = offsets[node0] + tid; e < e1; e += 256) {
    const int p = part[e];
    const int pos = atomicAdd(&cur[p & ((1 << BSHIFT) - 1)], 1);
    csr_src[pos] = p >> BSHIFT;
  }
}

// ---------------------------------------------------------------------------
// LDS-tiled GEMM: Hout[N, ldh](fp16) cols [c0,c0+COLS) = X[N,K](fp32) @ W.
// Same structure as round-3 kernel; epilogue converts to fp16.
// ---------------------------------------------------------------------------
template <int K, int COLS>
__global__ __launch_bounds__(256) void k_gemm(const float* __restrict__ X,
                                              const float* __restrict__ W, int ldw,
                                              int c0, __half* __restrict__ Hout,
                                              int ldh, int N) {
  constexpr int BM = 64;
  __shared__ float Xs[K * BM];    // transposed + swizzled
  __shared__ float Ws[K * COLS];  // [k][c] linear
  const int tid = threadIdx.x;

  for (int f = tid; f < (K * COLS) / 4; f += 256) {
    const int k = f / (COLS / 4);
    const int j4 = f % (COLS / 4);
    reinterpret_cast<float4*>(Ws)[f] =
        *reinterpret_cast<const float4*>(W + (size_t)k * ldw + c0 + j4 * 4);
  }

  const int row0 = blockIdx.x * BM;
  for (int f = tid; f < BM * (K / 4); f += 256) {
    const int r = f / (K / 4);
    const int k4 = f % (K / 4);
    const int row = row0 + r;
    float4 xv = (row < N)
                    ? *reinterpret_cast<const float4*>(X + (size_t)row * K + k4 * 4)
                    : float4{0.f, 0.f, 0.f, 0.f};
    const int cs = ((((r >> 2) ^ (k4 & 15)) << 2) | (r & 3));
#pragma unroll
    for (int j = 0; j < 4; ++j) Xs[(k4 * 4 + j) * BM + cs] = (&xv.x)[j];
  }
  __syncthreads();

  const int r0 = (tid >> 4) * 4;
  const int cc = (tid & 15) * 4;
  const int a = r0 >> 2;
  float acc[4][4] = {};

  for (int k4 = 0; k4 < K / 4; ++k4) {
    const int xbase = (k4 * 4) * BM + ((a ^ (k4 & 15)) << 2);
    const int wbase = (k4 * 4) * COLS + cc;
#pragma unroll
    for (int j = 0; j < 4; ++j) {
      const float4 xv = *reinterpret_cast<const float4*>(&Xs[xbase + j * BM]);
      const float4 wv = *reinterpret_cast<const float4*>(&Ws[wbase + j * COLS]);
#pragma unroll
      for (int i = 0; i < 4; ++i) {
        const float xi = (&xv.x)[i];
        acc[i][0] = fmaf(xi, wv.x, acc[i][0]);
        acc[i][1] = fmaf(xi, wv.y, acc[i][1]);
        acc[i][2] = fmaf(xi, wv.z, acc[i][2]);
        acc[i][3] = fmaf(xi, wv.w, acc[i][3]);
      }
    }
  }

#pragma unroll
  for (int i = 0; i < 4; ++i) {
    const int row = row0 + r0 + i;
    if (row < N) {
      __half2* hp = reinterpret_cast<__half2*>(Hout + (size_t)row * ldh + c0 + cc);
      hp[0] = __floats2half2_rn(acc[i][0], acc[i][1]);
      hp[1] = __floats2half2_rn(acc[i][2], acc[i][3]);
    }
  }
}

// CSR gather-aggregate (fp16 H, fp32 accumulate), fused self-loop+bias+relu.
// One wave per dst node. C=128: lane handles 2 channels (__half2).
template <int C>
__global__ __launch_bounds__(256) void k_gather(const __half* __restrict__ H,
                                                const int* __restrict__ offsets,
                                                const int* __restrict__ csr_src,
                                                const float* __restrict__ dinv,
                                                const float* __restrict__ bias,
                                                float* __restrict__ out, int N) {
  const int lane = threadIdx.x & 63;
  int w = (blockIdx.x * 256 + threadIdx.x) >> 6;
  const int nw = (gridDim.x * 256) >> 6;
  for (int i = w; i < N; i += nw) {
    const float di = dinv[i];
    float accx, accy = 0.f;
    if constexpr (C == 128) {
      const float2 f = __half22float2(
          *reinterpret_cast<const __half2*>(H + (size_t)i * 128 + lane * 2));
      accx = f.x * di * di;
      accy = f.y * di * di;
    } else {
      accx = __half2float(H[(size_t)i * 64 + lane]) * di * di;
    }
    const int beg = offsets[i];
    const int end = offsets[i + 1];
    int idx = beg;
    for (; idx + 1 < end; idx += 2) {
      const int s0 = csr_src[idx];
      const int s1 = csr_src[idx + 1];
      const float cf0 = dinv[s0] * di;
      const float cf1 = dinv[s1] * di;
      if constexpr (C == 128) {
        const float2 f0 = __half22float2(
            *reinterpret_cast<const __half2*>(H + (size_t)s0 * 128 + lane * 2));
        const float2 f1 = __half22float2(
            *reinterpret_cast<const __half2*>(H + (size_t)s1 * 128 + lane * 2));
        accx = fmaf(cf0, f0.x, accx);
        accy = fmaf(cf0, f0.y, accy);
        accx = fmaf(cf1, f1.x, accx);
        accy = fmaf(cf1, f1.y, accy);
      } else {
        accx = fmaf(cf0, __half2float(H[(size_t)s0 * 64 + lane]), accx);
        accx = fmaf(cf1, __half2float(H[(size_t)s1 * 64 + lane]), accx);
      }
    }
    if (idx < end) {
      const int s0 = csr_src[idx];
      const float cf0 = dinv[s0] * di;
      if constexpr (C == 128) {
        const float2 f0 = __half22float2(
            *reinterpret_cast<const __half2*>(H + (size_t)s0 * 128 + lane * 2));
        accx = fmaf(cf0, f0.x, accx);
        accy = fmaf(cf0, f0.y, accy);
      } else {
        accx = fmaf(cf0, __half2float(H[(size_t)s0 * 64 + lane]), accx);
      }
    }
    if constexpr (C == 128) {
      float2 o;
      o.x = fmaxf(accx + bias[lane * 2], 0.f);
      o.y = fmaxf(accy + bias[lane * 2 + 1], 0.f);
      *reinterpret_cast<float2*>(out + (size_t)i * 128 + lane * 2) = o;
    } else {
      out[(size_t)i * 64 + lane] = fmaxf(accx + bias[lane], 0.f);
    }
  }
}

extern "C" void kernel_launch(void* const* d_in, const int* in_sizes, int n_in,
                              void* d_out, int out_size, void* d_ws,
                              size_t ws_size, hipStream_t stream) {
  const float* x  = (const float*)d_in[0];
  const int*   ei = (const int*)d_in[1];
  const float* W1 = (const float*)d_in[2];
  const float* b1 = (const float*)d_in[3];
  const float* W2 = (const float*)d_in[4];
  const float* b2 = (const float*)d_in[5];

  const int IN  = 128;
  const int n   = in_sizes[0] / IN;   // 100000
  const int E   = in_sizes[1] / 2;    // 3200000
  const int HID = in_sizes[2] / IN;   // 128
  const int* srcv = ei;
  const int* dstv = ei + E;
  float* out = (float*)d_out;

  const int NB   = (n + 1023) / 1024;      // scan blocks (98)
  const int NBKT = (n + 255) >> BSHIFT;    // buckets (391)
  const int NT   = (n + 63) / 64;          // gemm tiles (1563)
  const int NCHK = (E + 4095) / 4096;      // partition chunks (782)

  // Workspace (~91 MB): part[] aliases bufHp (dead until gather1 writes it).
  char* p = (char*)d_ws;
  auto take = [&](size_t bytes) {
    char* r = p;
    p += (bytes + 255) & ~(size_t)255;
    return r;
  };
  float*  dinv      = (float*)take((size_t)n * 4);
  int*    counts    = (int*)take((size_t)n * 4);
  int*    offsets   = (int*)take((size_t)(n + 1) * 4);
  int*    bktcur    = (int*)take(512 * 4);
  int*    blocksums = (int*)take((size_t)((NB + 255) & ~255) * 4);
  int*    csr_src   = (int*)take((size_t)E * 4);            // 12.8 MB
  __half* H16       = (__half*)take((size_t)n * 128 * 2);   // 25.6 MB (H1; later H2)
  float*  bufHp     = (float*)take((size_t)n * HID * 4);    // 51.2 MB (h' fp32)
  int*    part      = (int*)bufHp;                          // 12.8 MB alias

  // --- degree + offsets ---
  hipMemsetAsync(counts, 0, (size_t)n * 4, stream);
  k_count<<<1024, 256, 0, stream>>>(dstv, counts, E);
  k_dinv<<<(n + 255) / 256, 256, 0, stream>>>(counts, dinv, n);
  k_scan1<<<NB, 256, 0, stream>>>(counts, offsets, blocksums, n);
  k_scan2<<<1, 256, 0, stream>>>(blocksums, NB);
  k_scan3<<<(n + 255) / 256, 256, 0, stream>>>(offsets, blocksums, n, E);

  // --- bucketed CSR fill ---
  k_bktinit<<<(NBKT + 255) / 256, 256, 0, stream>>>(offsets, bktcur, NBKT);
  k_part<<<NCHK, 256, 0, stream>>>(srcv, dstv, bktcur, part, E, NBKT);
  k_csr<<<NBKT, 256, 0, stream>>>(part, offsets, csr_src, n);

  // --- layer 1: H1 = x@W1 (fp16, two col-halves) ; one 128-ch gather ---
  k_gemm<128, 64><<<NT, 256, 0, stream>>>(x, W1, HID, 0, H16, 128, n);
  k_gemm<128, 64><<<NT, 256, 0, stream>>>(x, W1, HID, 64, H16, 128, n);
  k_gather<128><<<25000, 256, 0, stream>>>(H16, offsets, csr_src, dinv, b1,
                                           bufHp, n);

  // --- layer 2: H2 = h'@W2 (fp16, reuse H16) ; 64-ch gather -> d_out ---
  k_gemm<128, 64><<<NT, 256, 0, stream>>>(bufHp, W2, 64, 0, H16, 64, n);
  k_gather<64><<<25000, 256, 0, stream>>>(H16, offsets, csr_src, dinv, b2,
                                          out, n);
}

// Round 8
// 429.617 us; speedup vs baseline: 9.5118x; 1.6703x over previous
//
#include <hip/hip_runtime.h>
#include <hip/hip_fp16.h>
#include <cstdint>
#include <cstddef>

// ---------------------------------------------------------------------------
// 2-layer GCN (PyG GCNConv semantics) on MI355X.
// Round 8: (A) wide gather - 8 edge slots x 8-lane channel groups per wave,
// dwordx4 fp16 loads, shfl-reduce; (B) CSR build with LDS-only node atomics
// (bucket hist -> bucket scan -> partition -> per-bucket count/scan/scatter).
// ---------------------------------------------------------------------------

#define BSHIFT 8  // 256 nodes per bucket

// Pass A: per-bucket histogram (LDS-merged).
__global__ __launch_bounds__(256) void k_hist(const int* __restrict__ dst,
                                              int* __restrict__ bkthist, int E) {
  __shared__ int h[512];
  for (int t = threadIdx.x; t < 512; t += 256) h[t] = 0;
  __syncthreads();
  int i = blockIdx.x * 256 + threadIdx.x;
  const int stride = gridDim.x * 256;
  for (; i < E; i += stride) atomicAdd(&h[dst[i] >> BSHIFT], 1);
  __syncthreads();
  for (int t = threadIdx.x; t < 512; t += 256)
    if (h[t]) atomicAdd(&bkthist[t], h[t]);
}

// Bucket exclusive scan (1 block). Also sets offsets[n]=E and bktbase[nbkt]=E.
__global__ __launch_bounds__(256) void k_bktscan(const int* __restrict__ bkthist,
                                                 int* __restrict__ bktbase,
                                                 int* __restrict__ bktcur,
                                                 int* __restrict__ offsets, int n,
                                                 int E, int nbkt) {
  __shared__ int sc[512];
  const int t = threadIdx.x;
  sc[t] = (t < nbkt) ? bkthist[t] : 0;
  sc[256 + t] = (256 + t < nbkt) ? bkthist[256 + t] : 0;
  __syncthreads();
  if (t == 0) {
    int run = 0;
    for (int b = 0; b < nbkt; ++b) {
      const int c = sc[b];
      sc[b] = run;
      run += c;
    }
    offsets[n] = E;
    bktbase[nbkt] = E;
  }
  __syncthreads();
  if (t < nbkt) {
    bktbase[t] = sc[t];
    bktcur[t] = sc[t];
  }
  if (256 + t < nbkt) {
    bktbase[256 + t] = sc[256 + t];
    bktcur[256 + t] = sc[256 + t];
  }
}

// Pass B: partition edges by dst-bucket into part[] (packed (src<<8)|dst_low).
__global__ __launch_bounds__(256) void k_part(const int* __restrict__ src,
                                              const int* __restrict__ dst,
                                              int* __restrict__ bktcur,
                                              int* __restrict__ part, int E,
                                              int nbkt) {
  __shared__ int hist[512];
  const int tid = threadIdx.x;
  const int e0 = blockIdx.x * 4096;
  for (int b = tid; b < nbkt; b += 256) hist[b] = 0;
  __syncthreads();
#pragma unroll
  for (int j = 0; j < 16; ++j) {
    const int e = e0 + j * 256 + tid;
    if (e < E) atomicAdd(&hist[dst[e] >> BSHIFT], 1);
  }
  __syncthreads();
  for (int b = tid; b < nbkt; b += 256) {
    const int c = hist[b];
    hist[b] = c ? atomicAdd(&bktcur[b], c) : 0;  // hist becomes running cursor
  }
  __syncthreads();
#pragma unroll
  for (int j = 0; j < 16; ++j) {
    const int e = e0 + j * 256 + tid;
    if (e < E) {
      const int d = dst[e];
      const int pos = atomicAdd(&hist[d >> BSHIFT], 1);
      part[pos] = (src[e] << BSHIFT) | (d & ((1 << BSHIFT) - 1));
    }
  }
}

// Pass C: per bucket - LDS per-node count, LDS scan -> offsets + dinv, then
// scatter src into final CSR slots (LDS cursors, L2-local window writes).
__global__ __launch_bounds__(256) void k_csr2(const int* __restrict__ part,
                                              const int* __restrict__ bktbase,
                                              int* __restrict__ offsets,
                                              int* __restrict__ csr_src,
                                              float* __restrict__ dinv, int n) {
  __shared__ int cnt[256];
  __shared__ int ts[256];
  const int b = blockIdx.x;
  const int node0 = b << BSHIFT;
  const int nn = min(256, n - node0);
  const int t = threadIdx.x;
  cnt[t] = 0;
  __syncthreads();
  const int w0 = bktbase[b];
  const int w1 = bktbase[b + 1];
  for (int e = w0 + t; e < w1; e += 256)
    atomicAdd(&cnt[part[e] & ((1 << BSHIFT) - 1)], 1);
  __syncthreads();
  const int c = cnt[t];
  ts[t] = c;
  __syncthreads();
  for (int off = 1; off < 256; off <<= 1) {
    const int u = (t >= off) ? ts[t - off] : 0;
    __syncthreads();
    ts[t] += u;
    __syncthreads();
  }
  const int excl = ts[t] - c;
  if (t < nn) {
    offsets[node0 + t] = w0 + excl;
    dinv[node0 + t] = rsqrtf((float)c + 1.0f);
  }
  cnt[t] = w0 + excl;  // becomes cursor
  __syncthreads();
  for (int e = w0 + t; e < w1; e += 256) {
    const int p = part[e];
    const int pos = atomicAdd(&cnt[p & ((1 << BSHIFT) - 1)], 1);
    csr_src[pos] = p >> BSHIFT;
  }
}

// ---------------------------------------------------------------------------
// LDS-tiled GEMM: Hout[N, ldh](fp16) cols [c0,c0+COLS) = X[N,K](fp32) @ W.
// ---------------------------------------------------------------------------
template <int K, int COLS>
__global__ __launch_bounds__(256) void k_gemm(const float* __restrict__ X,
                                              const float* __restrict__ W, int ldw,
                                              int c0, __half* __restrict__ Hout,
                                              int ldh, int N) {
  constexpr int BM = 64;
  __shared__ float Xs[K * BM];    // transposed + swizzled
  __shared__ float Ws[K * COLS];  // [k][c] linear
  const int tid = threadIdx.x;

  for (int f = tid; f < (K * COLS) / 4; f += 256) {
    const int k = f / (COLS / 4);
    const int j4 = f % (COLS / 4);
    reinterpret_cast<float4*>(Ws)[f] =
        *reinterpret_cast<const float4*>(W + (size_t)k * ldw + c0 + j4 * 4);
  }

  const int row0 = blockIdx.x * BM;
  for (int f = tid; f < BM * (K / 4); f += 256) {
    const int r = f / (K / 4);
    const int k4 = f % (K / 4);
    const int row = row0 + r;
    float4 xv = (row < N)
                    ? *reinterpret_cast<const float4*>(X + (size_t)row * K + k4 * 4)
                    : float4{0.f, 0.f, 0.f, 0.f};
    const int cs = ((((r >> 2) ^ (k4 & 15)) << 2) | (r & 3));
#pragma unroll
    for (int j = 0; j < 4; ++j) Xs[(k4 * 4 + j) * BM + cs] = (&xv.x)[j];
  }
  __syncthreads();

  const int r0 = (tid >> 4) * 4;
  const int cc = (tid & 15) * 4;
  const int a = r0 >> 2;
  float acc[4][4] = {};

  for (int k4 = 0; k4 < K / 4; ++k4) {
    const int xbase = (k4 * 4) * BM + ((a ^ (k4 & 15)) << 2);
    const int wbase = (k4 * 4) * COLS + cc;
#pragma unroll
    for (int j = 0; j < 4; ++j) {
      const float4 xv = *reinterpret_cast<const float4*>(&Xs[xbase + j * BM]);
      const float4 wv = *reinterpret_cast<const float4*>(&Ws[wbase + j * COLS]);
#pragma unroll
      for (int i = 0; i < 4; ++i) {
        const float xi = (&xv.x)[i];
        acc[i][0] = fmaf(xi, wv.x, acc[i][0]);
        acc[i][1] = fmaf(xi, wv.y, acc[i][1]);
        acc[i][2] = fmaf(xi, wv.z, acc[i][2]);
        acc[i][3] = fmaf(xi, wv.w, acc[i][3]);
      }
    }
  }

#pragma unroll
  for (int i = 0; i < 4; ++i) {
    const int row = row0 + r0 + i;
    if (row < N) {
      __half2* hp = reinterpret_cast<__half2*>(Hout + (size_t)row * ldh + c0 + cc);
      hp[0] = __floats2half2_rn(acc[i][0], acc[i][1]);
      hp[1] = __floats2half2_rn(acc[i][2], acc[i][3]);
    }
  }
}

// ---------------------------------------------------------------------------
// Wide CSR gather (fp16 H, fp32 acc), fused self-loop + bias + relu.
// One wave per node. lane = (g<<3)|sl: g = edge slot (8 edges in flight),
// sl = channel block. 128ch: sl covers 16 ch (2x dwordx4). 64ch: 8 ch (1x).
// Cross-group reduce via shfl_xor(8/16/32); group 0 writes the output.
// ---------------------------------------------------------------------------
__global__ __launch_bounds__(256) void k_gather128(
    const __half* __restrict__ H, const int* __restrict__ offsets,
    const int* __restrict__ csr_src, const float* __restrict__ dinv,
    const float* __restrict__ bias, float* __restrict__ out, int N) {
  const int lane = threadIdx.x & 63;
  const int g = lane >> 3;  // 0..7 edge slot
  const int sl = lane & 7;  // 0..7 channel block (16 ch)
  int w = (blockIdx.x * 256 + threadIdx.x) >> 6;
  const int nw = (gridDim.x * 256) >> 6;
  for (int i = w; i < N; i += nw) {
    const float di = dinv[i];
    const int beg = offsets[i];
    const int end = offsets[i + 1];
    float acc[16];
    {
      const float cfs = (g == 0) ? di * di : 0.f;
      const float4 ha = *reinterpret_cast<const float4*>(H + (size_t)i * 128 + sl * 16);
      const float4 hb = *reinterpret_cast<const float4*>(H + (size_t)i * 128 + sl * 16 + 8);
      const __half2* hpa = reinterpret_cast<const __half2*>(&ha);
      const __half2* hpb = reinterpret_cast<const __half2*>(&hb);
#pragma unroll
      for (int q = 0; q < 4; ++q) {
        const float2 fa = __half22float2(hpa[q]);
        const float2 fb = __half22float2(hpb[q]);
        acc[q * 2] = cfs * fa.x;
        acc[q * 2 + 1] = cfs * fa.y;
        acc[8 + q * 2] = cfs * fb.x;
        acc[8 + q * 2 + 1] = cfs * fb.y;
      }
    }
    for (int base = beg; base < end; base += 8) {
      const int e = base + g;
      const bool v = e < end;
      const int s = v ? csr_src[e] : i;
      const float cf = v ? dinv[s] * di : 0.f;
      const float4 ha = *reinterpret_cast<const float4*>(H + (size_t)s * 128 + sl * 16);
      const float4 hb = *reinterpret_cast<const float4*>(H + (size_t)s * 128 + sl * 16 + 8);
      const __half2* hpa = reinterpret_cast<const __half2*>(&ha);
      const __half2* hpb = reinterpret_cast<const __half2*>(&hb);
#pragma unroll
      for (int q = 0; q < 4; ++q) {
        const float2 fa = __half22float2(hpa[q]);
        const float2 fb = __half22float2(hpb[q]);
        acc[q * 2] = fmaf(cf, fa.x, acc[q * 2]);
        acc[q * 2 + 1] = fmaf(cf, fa.y, acc[q * 2 + 1]);
        acc[8 + q * 2] = fmaf(cf, fb.x, acc[8 + q * 2]);
        acc[8 + q * 2 + 1] = fmaf(cf, fb.y, acc[8 + q * 2 + 1]);
      }
    }
#pragma unroll
    for (int j = 0; j < 16; ++j) {
      float a = acc[j];
      a += __shfl_xor(a, 8);
      a += __shfl_xor(a, 16);
      a += __shfl_xor(a, 32);
      acc[j] = a;
    }
    if (g == 0) {
      float* op = out + (size_t)i * 128 + sl * 16;
      const float4 b0 = *reinterpret_cast<const float4*>(bias + sl * 16);
      const float4 b1 = *reinterpret_cast<const float4*>(bias + sl * 16 + 4);
      const float4 b2 = *reinterpret_cast<const float4*>(bias + sl * 16 + 8);
      const float4 b3 = *reinterpret_cast<const float4*>(bias + sl * 16 + 12);
      float4 o;
      o.x = fmaxf(acc[0] + b0.x, 0.f);
      o.y = fmaxf(acc[1] + b0.y, 0.f);
      o.z = fmaxf(acc[2] + b0.z, 0.f);
      o.w = fmaxf(acc[3] + b0.w, 0.f);
      *reinterpret_cast<float4*>(op) = o;
      o.x = fmaxf(acc[4] + b1.x, 0.f);
      o.y = fmaxf(acc[5] + b1.y, 0.f);
      o.z = fmaxf(acc[6] + b1.z, 0.f);
      o.w = fmaxf(acc[7] + b1.w, 0.f);
      *reinterpret_cast<float4*>(op + 4) = o;
      o.x = fmaxf(acc[8] + b2.x, 0.f);
      o.y = fmaxf(acc[9] + b2.y, 0.f);
      o.z = fmaxf(acc[10] + b2.z, 0.f);
      o.w = fmaxf(acc[11] + b2.w, 0.f);
      *reinterpret_cast<float4*>(op + 8) = o;
      o.x = fmaxf(acc[12] + b3.x, 0.f);
      o.y = fmaxf(acc[13] + b3.y, 0.f);
      o.z = fmaxf(acc[14] + b3.z, 0.f);
      o.w = fmaxf(acc[15] + b3.w, 0.f);
      *reinterpret_cast<float4*>(op + 12) = o;
    }
  }
}

__global__ __launch_bounds__(256) void k_gather64(
    const __half* __restrict__ H, const int* __restrict__ offsets,
    const int* __restrict__ csr_src, const float* __restrict__ dinv,
    const float* __restrict__ bias, float* __restrict__ out, int N) {
  const int lane = threadIdx.x & 63;
  const int g = lane >> 3;  // 0..7 edge slot
  const int sl = lane & 7;  // 0..7 channel block (8 ch)
  int w = (blockIdx.x * 256 + threadIdx.x) >> 6;
  const int nw = (gridDim.x * 256) >> 6;
  for (int i = w; i < N; i += nw) {
    const float di = dinv[i];
    const int beg = offsets[i];
    const int end = offsets[i + 1];
    float acc[8];
    {
      const float cfs = (g == 0) ? di * di : 0.f;
      const float4 ha = *reinterpret_cast<const float4*>(H + (size_t)i * 64 + sl * 8);
      const __half2* hpa = reinterpret_cast<const __half2*>(&ha);
#pragma unroll
      for (int q = 0; q < 4; ++q) {
        const float2 fa = __half22float2(hpa[q]);
        acc[q * 2] = cfs * fa.x;
        acc[q * 2 + 1] = cfs * fa.y;
      }
    }
    for (int base = beg; base < end; base += 8) {
      const int e = base + g;
      const bool v = e < end;
      const int s = v ? csr_src[e] : i;
      const float cf = v ? dinv[s] * di : 0.f;
      const float4 ha = *reinterpret_cast<const float4*>(H + (size_t)s * 64 + sl * 8);
      const __half2* hpa = reinterpret_cast<const __half2*>(&ha);
#pragma unroll
      for (int q = 0; q < 4; ++q) {
        const float2 fa = __half22float2(hpa[q]);
        acc[q * 2] = fmaf(cf, fa.x, acc[q * 2]);
        acc[q * 2 + 1] = fmaf(cf, fa.y, acc[q * 2 + 1]);
      }
    }
#pragma unroll
    for (int j = 0; j < 8; ++j) {
      float a = acc[j];
      a += __shfl_xor(a, 8);
      a += __shfl_xor(a, 16);
      a += __shfl_xor(a, 32);
      acc[j] = a;
    }
    if (g == 0) {
      float* op = out + (size_t)i * 64 + sl * 8;
      const float4 b0 = *reinterpret_cast<const float4*>(bias + sl * 8);
      const float4 b1 = *reinterpret_cast<const float4*>(bias + sl * 8 + 4);
      float4 o;
      o.x = fmaxf(acc[0] + b0.x, 0.f);
      o.y = fmaxf(acc[1] + b0.y, 0.f);
      o.z = fmaxf(acc[2] + b0.z, 0.f);
      o.w = fmaxf(acc[3] + b0.w, 0.f);
      *reinterpret_cast<float4*>(op) = o;
      o.x = fmaxf(acc[4] + b1.x, 0.f);
      o.y = fmaxf(acc[5] + b1.y, 0.f);
      o.z = fmaxf(acc[6] + b1.z, 0.f);
      o.w = fmaxf(acc[7] + b1.w, 0.f);
      *reinterpret_cast<float4*>(op + 4) = o;
    }
  }
}

extern "C" void kernel_launch(void* const* d_in, const int* in_sizes, int n_in,
                              void* d_out, int out_size, void* d_ws,
                              size_t ws_size, hipStream_t stream) {
  const float* x  = (const float*)d_in[0];
  const int*   ei = (const int*)d_in[1];
  const float* W1 = (const float*)d_in[2];
  const float* b1 = (const float*)d_in[3];
  const float* W2 = (const float*)d_in[4];
  const float* b2 = (const float*)d_in[5];

  const int IN  = 128;
  const int n   = in_sizes[0] / IN;   // 100000
  const int E   = in_sizes[1] / 2;    // 3200000
  const int HID = in_sizes[2] / IN;   // 128
  const int* srcv = ei;
  const int* dstv = ei + E;
  float* out = (float*)d_out;

  const int NBKT = (n + 255) >> BSHIFT;    // buckets (391)
  const int NT   = (n + 63) / 64;          // gemm tiles (1563)
  const int NCHK = (E + 4095) / 4096;      // partition chunks (782)

  // Workspace (~90.5 MB): part[] aliases bufHp (dead until gather128 writes it).
  char* p = (char*)d_ws;
  auto take = [&](size_t bytes) {
    char* r = p;
    p += (bytes + 255) & ~(size_t)255;
    return r;
  };
  float*  dinv    = (float*)take((size_t)n * 4);
  int*    offsets = (int*)take((size_t)(n + 1) * 4);
  int*    bkthist = (int*)take(512 * 4);
  int*    bktbase = (int*)take(512 * 4);
  int*    bktcur  = (int*)take(512 * 4);
  int*    csr_src = (int*)take((size_t)E * 4);            // 12.8 MB
  __half* H16     = (__half*)take((size_t)n * 128 * 2);   // 25.6 MB (H1; later H2)
  float*  bufHp   = (float*)take((size_t)n * HID * 4);    // 51.2 MB (h' fp32)
  int*    part    = (int*)bufHp;                          // 12.8 MB alias

  // --- CSR build (no per-node global atomics) ---
  hipMemsetAsync(bkthist, 0, 512 * 4, stream);
  k_hist<<<1024, 256, 0, stream>>>(dstv, bkthist, E);
  k_bktscan<<<1, 256, 0, stream>>>(bkthist, bktbase, bktcur, offsets, n, E, NBKT);
  k_part<<<NCHK, 256, 0, stream>>>(srcv, dstv, bktcur, part, E, NBKT);
  k_csr2<<<NBKT, 256, 0, stream>>>(part, bktbase, offsets, csr_src, dinv, n);

  // --- layer 1: H1 = x@W1 (fp16, two col-halves) ; one 128-ch gather ---
  k_gemm<128, 64><<<NT, 256, 0, stream>>>(x, W1, HID, 0, H16, 128, n);
  k_gemm<128, 64><<<NT, 256, 0, stream>>>(x, W1, HID, 64, H16, 128, n);
  k_gather128<<<25000, 256, 0, stream>>>(H16, offsets, csr_src, dinv, b1,
                                         bufHp, n);

  // --- layer 2: H2 = h'@W2 (fp16, reuse H16) ; 64-ch gather -> d_out ---
  k_gemm<128, 64><<<NT, 256, 0, stream>>>(bufHp, W2, 64, 0, H16, 64, n);
  k_gather64<<<25000, 256, 0, stream>>>(H16, offsets, csr_src, dinv, b2,
                                        out, n);
}

// Round 9
// 360.654 us; speedup vs baseline: 11.3306x; 1.1912x over previous
//
#include <hip/hip_runtime.h>
#include <hip/hip_fp16.h>
#include <cstdint>
#include <cstddef>

// ---------------------------------------------------------------------------
// 2-layer GCN (PyG GCNConv semantics) on MI355X.
// Round 9: MFMA fp16 GEMM (16x16x32, W^T swizzled in LDS, B-frags in regs,
// LDS-bounce epilogue). Layer-1 GEMM does all 128 cols in one pass reading x
// once, converting fp32->fp16 in-kernel. Gathers + CSR build unchanged.
// ---------------------------------------------------------------------------

#define BSHIFT 8  // 256 nodes per bucket

typedef _Float16 half8 __attribute__((ext_vector_type(8)));
typedef float f32x4 __attribute__((ext_vector_type(4)));

// Pass A: per-bucket histogram (LDS-merged).
__global__ __launch_bounds__(256) void k_hist(const int* __restrict__ dst,
                                              int* __restrict__ bkthist, int E) {
  __shared__ int h[512];
  for (int t = threadIdx.x; t < 512; t += 256) h[t] = 0;
  __syncthreads();
  int i = blockIdx.x * 256 + threadIdx.x;
  const int stride = gridDim.x * 256;
  for (; i < E; i += stride) atomicAdd(&h[dst[i] >> BSHIFT], 1);
  __syncthreads();
  for (int t = threadIdx.x; t < 512; t += 256)
    if (h[t]) atomicAdd(&bkthist[t], h[t]);
}

// Bucket exclusive scan (1 block). Also sets offsets[n]=E and bktbase[nbkt]=E.
__global__ __launch_bounds__(256) void k_bktscan(const int* __restrict__ bkthist,
                                                 int* __restrict__ bktbase,
                                                 int* __restrict__ bktcur,
                                                 int* __restrict__ offsets, int n,
                                                 int E, int nbkt) {
  __shared__ int sc[512];
  const int t = threadIdx.x;
  sc[t] = (t < nbkt) ? bkthist[t] : 0;
  sc[256 + t] = (256 + t < nbkt) ? bkthist[256 + t] : 0;
  __syncthreads();
  if (t == 0) {
    int run = 0;
    for (int b = 0; b < nbkt; ++b) {
      const int c = sc[b];
      sc[b] = run;
      run += c;
    }
    offsets[n] = E;
    bktbase[nbkt] = E;
  }
  __syncthreads();
  if (t < nbkt) {
    bktbase[t] = sc[t];
    bktcur[t] = sc[t];
  }
  if (256 + t < nbkt) {
    bktbase[256 + t] = sc[256 + t];
    bktcur[256 + t] = sc[256 + t];
  }
}

// Pass B: partition edges by dst-bucket into part[] (packed (src<<8)|dst_low).
__global__ __launch_bounds__(256) void k_part(const int* __restrict__ src,
                                              const int* __restrict__ dst,
                                              int* __restrict__ bktcur,
                                              int* __restrict__ part, int E,
                                              int nbkt) {
  __shared__ int hist[512];
  const int tid = threadIdx.x;
  const int e0 = blockIdx.x * 4096;
  for (int b = tid; b < nbkt; b += 256) hist[b] = 0;
  __syncthreads();
#pragma unroll
  for (int j = 0; j < 16; ++j) {
    const int e = e0 + j * 256 + tid;
    if (e < E) atomicAdd(&hist[dst[e] >> BSHIFT], 1);
  }
  __syncthreads();
  for (int b = tid; b < nbkt; b += 256) {
    const int c = hist[b];
    hist[b] = c ? atomicAdd(&bktcur[b], c) : 0;  // hist becomes running cursor
  }
  __syncthreads();
#pragma unroll
  for (int j = 0; j < 16; ++j) {
    const int e = e0 + j * 256 + tid;
    if (e < E) {
      const int d = dst[e];
      const int pos = atomicAdd(&hist[d >> BSHIFT], 1);
      part[pos] = (src[e] << BSHIFT) | (d & ((1 << BSHIFT) - 1));
    }
  }
}

// Pass C: per bucket - LDS per-node count, LDS scan -> offsets + dinv, then
// scatter src into final CSR slots (LDS cursors, L2-local window writes).
__global__ __launch_bounds__(256) void k_csr2(const int* __restrict__ part,
                                              const int* __restrict__ bktbase,
                                              int* __restrict__ offsets,
                                              int* __restrict__ csr_src,
                                              float* __restrict__ dinv, int n) {
  __shared__ int cnt[256];
  __shared__ int ts[256];
  const int b = blockIdx.x;
  const int node0 = b << BSHIFT;
  const int nn = min(256, n - node0);
  const int t = threadIdx.x;
  cnt[t] = 0;
  __syncthreads();
  const int w0 = bktbase[b];
  const int w1 = bktbase[b + 1];
  for (int e = w0 + t; e < w1; e += 256)
    atomicAdd(&cnt[part[e] & ((1 << BSHIFT) - 1)], 1);
  __syncthreads();
  const int c = cnt[t];
  ts[t] = c;
  __syncthreads();
  for (int off = 1; off < 256; off <<= 1) {
    const int u = (t >= off) ? ts[t - off] : 0;
    __syncthreads();
    ts[t] += u;
    __syncthreads();
  }
  const int excl = ts[t] - c;
  if (t < nn) {
    offsets[node0 + t] = w0 + excl;
    dinv[node0 + t] = rsqrtf((float)c + 1.0f);
  }
  cnt[t] = w0 + excl;  // becomes cursor
  __syncthreads();
  for (int e = w0 + t; e < w1; e += 256) {
    const int p = part[e];
    const int pos = atomicAdd(&cnt[p & ((1 << BSHIFT) - 1)], 1);
    csr_src[pos] = p >> BSHIFT;
  }
}

// ---------------------------------------------------------------------------
// MFMA fp16 GEMM: Hout[N,COLS](fp16) = A[N,128] @ W[128,COLS], f32 accumulate.
// TA = float (in-kernel cvt to fp16) or __half.
// 4 waves. COLS=128: wave = (row-half, col-half), 32 rows/tile.
//          COLS=64 : wave = row quarter, 64 rows/tile.
// W^T staged once per block in LDS (fp16, XOR-swizzled); B-frags in VGPRs;
// per-wave LDS bounce epilogue for coalesced fp16 stores.
// ---------------------------------------------------------------------------
template <typename TA, int COLS>
__global__ __launch_bounds__(256) void k_gemm_mfma(const TA* __restrict__ A,
                                                   const float* __restrict__ W,
                                                   __half* __restrict__ Hout,
                                                   int N, int ntiles) {
  constexpr int RW = (COLS == 128) ? 2 : 4;  // row-waves per tile
  constexpr int RPT = RW * 16;               // rows per tile
  __shared__ _Float16 Wt[128 * COLS];
  __shared__ _Float16 Lb[4][16][72];
  const int tid = threadIdx.x;
  const int w = tid >> 6;
  const int l = tid & 63;

  // stage W^T fp16 swizzled: Wt[(c*128+k) ^ ((c&7)<<3)]
  for (int f = tid; f < (128 * COLS) / 4; f += 256) {
    const int k = f / (COLS / 4);
    const int c4 = (f % (COLS / 4)) * 4;
    const float4 wv = *reinterpret_cast<const float4*>(W + (size_t)k * COLS + c4);
#pragma unroll
    for (int j = 0; j < 4; ++j) {
      const int cc = c4 + j;
      Wt[(cc * 128 + k) ^ ((cc & 7) << 3)] = (_Float16)(&wv.x)[j];
    }
  }
  __syncthreads();

  const int colw = (COLS == 128) ? (w >> 1) * 64 : 0;
  const int rw = (COLS == 128) ? (w & 1) : w;
  const int koff = (l >> 4) * 8;

  // preload B fragments: B[k][c], lane: c = colw+16t+(l&15), k = 32s+koff+j
  half8 bf[4][4];
#pragma unroll
  for (int t = 0; t < 4; ++t)
#pragma unroll
    for (int s = 0; s < 4; ++s) {
      const int cc = colw + 16 * t + (l & 15);
      const int kk = 32 * s + koff;
      bf[t][s] =
          *reinterpret_cast<const half8*>(&Wt[(cc * 128 + kk) ^ ((cc & 7) << 3)]);
    }

  for (int tile = blockIdx.x; tile < ntiles; tile += gridDim.x) {
    const int row = tile * RPT + rw * 16 + (l & 15);
    const int rowc = (row < N) ? row : (N - 1);
    f32x4 acc[4];
#pragma unroll
    for (int t = 0; t < 4; ++t) acc[t] = (f32x4){0.f, 0.f, 0.f, 0.f};

#pragma unroll
    for (int s = 0; s < 4; ++s) {
      half8 af;
      if constexpr (sizeof(TA) == 4) {
        const float* ap = (const float*)A + (size_t)rowc * 128 + 32 * s + koff;
        const float4 a0 = *reinterpret_cast<const float4*>(ap);
        const float4 a1 = *reinterpret_cast<const float4*>(ap + 4);
#pragma unroll
        for (int j = 0; j < 4; ++j) {
          af[j] = (_Float16)(&a0.x)[j];
          af[4 + j] = (_Float16)(&a1.x)[j];
        }
      } else {
        af = *reinterpret_cast<const half8*>((const __half*)A +
                                             (size_t)rowc * 128 + 32 * s + koff);
      }
#pragma unroll
      for (int t = 0; t < 4; ++t)
        acc[t] = __builtin_amdgcn_mfma_f32_16x16x32_f16(af, bf[t][s], acc[t],
                                                        0, 0, 0);
    }

    // epilogue: C/D frag (col=l&15, row=(l>>4)*4+r) -> LDS bounce -> coalesced
#pragma unroll
    for (int t = 0; t < 4; ++t)
#pragma unroll
      for (int r = 0; r < 4; ++r)
        Lb[w][(l >> 4) * 4 + r][16 * t + (l & 15)] = (_Float16)acc[t][r];
    const int orow = tile * RPT + rw * 16 + (l & 15);
    if (orow < N) {
      const int ch = (l >> 4) * 16;
      const half8 v0 = *reinterpret_cast<const half8*>(&Lb[w][l & 15][ch]);
      const half8 v1 = *reinterpret_cast<const half8*>(&Lb[w][l & 15][ch + 8]);
      __half* hp = Hout + (size_t)orow * COLS + colw + ch;
      *reinterpret_cast<half8*>(hp) = v0;
      *reinterpret_cast<half8*>(hp + 8) = v1;
    }
  }
}

// ---------------------------------------------------------------------------
// Wide CSR gather (fp16 H, fp32 acc), fused self-loop + bias + relu.
// One wave per node. lane = (g<<3)|sl: g = edge slot (8 edges in flight),
// sl = channel block. 128ch: sl covers 16 ch (2x dwordx4). 64ch: 8 ch (1x).
// ---------------------------------------------------------------------------
__global__ __launch_bounds__(256) void k_gather128(
    const __half* __restrict__ H, const int* __restrict__ offsets,
    const int* __restrict__ csr_src, const float* __restrict__ dinv,
    const float* __restrict__ bias, float* __restrict__ out, int N) {
  const int lane = threadIdx.x & 63;
  const int g = lane >> 3;  // 0..7 edge slot
  const int sl = lane & 7;  // 0..7 channel block (16 ch)
  int w = (blockIdx.x * 256 + threadIdx.x) >> 6;
  const int nw = (gridDim.x * 256) >> 6;
  for (int i = w; i < N; i += nw) {
    const float di = dinv[i];
    const int beg = offsets[i];
    const int end = offsets[i + 1];
    float acc[16];
    {
      const float cfs = (g == 0) ? di * di : 0.f;
      const float4 ha = *reinterpret_cast<const float4*>(H + (size_t)i * 128 + sl * 16);
      const float4 hb = *reinterpret_cast<const float4*>(H + (size_t)i * 128 + sl * 16 + 8);
      const __half2* hpa = reinterpret_cast<const __half2*>(&ha);
      const __half2* hpb = reinterpret_cast<const __half2*>(&hb);
#pragma unroll
      for (int q = 0; q < 4; ++q) {
        const float2 fa = __half22float2(hpa[q]);
        const float2 fb = __half22float2(hpb[q]);
        acc[q * 2] = cfs * fa.x;
        acc[q * 2 + 1] = cfs * fa.y;
        acc[8 + q * 2] = cfs * fb.x;
        acc[8 + q * 2 + 1] = cfs * fb.y;
      }
    }
    for (int base = beg; base < end; base += 8) {
      const int e = base + g;
      const bool v = e < end;
      const int s = v ? csr_src[e] : i;
      const float cf = v ? dinv[s] * di : 0.f;
      const float4 ha = *reinterpret_cast<const float4*>(H + (size_t)s * 128 + sl * 16);
      const float4 hb = *reinterpret_cast<const float4*>(H + (size_t)s * 128 + sl * 16 + 8);
      const __half2* hpa = reinterpret_cast<const __half2*>(&ha);
      const __half2* hpb = reinterpret_cast<const __half2*>(&hb);
#pragma unroll
      for (int q = 0; q < 4; ++q) {
        const float2 fa = __half22float2(hpa[q]);
        const float2 fb = __half22float2(hpb[q]);
        acc[q * 2] = fmaf(cf, fa.x, acc[q * 2]);
        acc[q * 2 + 1] = fmaf(cf, fa.y, acc[q * 2 + 1]);
        acc[8 + q * 2] = fmaf(cf, fb.x, acc[8 + q * 2]);
        acc[8 + q * 2 + 1] = fmaf(cf, fb.y, acc[8 + q * 2 + 1]);
      }
    }
#pragma unroll
    for (int j = 0; j < 16; ++j) {
      float a = acc[j];
      a += __shfl_xor(a, 8);
      a += __shfl_xor(a, 16);
      a += __shfl_xor(a, 32);
      acc[j] = a;
    }
    if (g == 0) {
      float* op = out + (size_t)i * 128 + sl * 16;
      const float4 b0 = *reinterpret_cast<const float4*>(bias + sl * 16);
      const float4 b1 = *reinterpret_cast<const float4*>(bias + sl * 16 + 4);
      const float4 b2 = *reinterpret_cast<const float4*>(bias + sl * 16 + 8);
      const float4 b3 = *reinterpret_cast<const float4*>(bias + sl * 16 + 12);
      float4 o;
      o.x = fmaxf(acc[0] + b0.x, 0.f);
      o.y = fmaxf(acc[1] + b0.y, 0.f);
      o.z = fmaxf(acc[2] + b0.z, 0.f);
      o.w = fmaxf(acc[3] + b0.w, 0.f);
      *reinterpret_cast<float4*>(op) = o;
      o.x = fmaxf(acc[4] + b1.x, 0.f);
      o.y = fmaxf(acc[5] + b1.y, 0.f);
      o.z = fmaxf(acc[6] + b1.z, 0.f);
      o.w = fmaxf(acc[7] + b1.w, 0.f);
      *reinterpret_cast<float4*>(op + 4) = o;
      o.x = fmaxf(acc[8] + b2.x, 0.f);
      o.y = fmaxf(acc[9] + b2.y, 0.f);
      o.z = fmaxf(acc[10] + b2.z, 0.f);
      o.w = fmaxf(acc[11] + b2.w, 0.f);
      *reinterpret_cast<float4*>(op + 8) = o;
      o.x = fmaxf(acc[12] + b3.x, 0.f);
      o.y = fmaxf(acc[13] + b3.y, 0.f);
      o.z = fmaxf(acc[14] + b3.z, 0.f);
      o.w = fmaxf(acc[15] + b3.w, 0.f);
      *reinterpret_cast<float4*>(op + 12) = o;
    }
  }
}

__global__ __launch_bounds__(256) void k_gather64(
    const __half* __restrict__ H, const int* __restrict__ offsets,
    const int* __restrict__ csr_src, const float* __restrict__ dinv,
    const float* __restrict__ bias, float* __restrict__ out, int N) {
  const int lane = threadIdx.x & 63;
  const int g = lane >> 3;  // 0..7 edge slot
  const int sl = lane & 7;  // 0..7 channel block (8 ch)
  int w = (blockIdx.x * 256 + threadIdx.x) >> 6;
  const int nw = (gridDim.x * 256) >> 6;
  for (int i = w; i < N; i += nw) {
    const float di = dinv[i];
    const int beg = offsets[i];
    const int end = offsets[i + 1];
    float acc[8];
    {
      const float cfs = (g == 0) ? di * di : 0.f;
      const float4 ha = *reinterpret_cast<const float4*>(H + (size_t)i * 64 + sl * 8);
      const __half2* hpa = reinterpret_cast<const __half2*>(&ha);
#pragma unroll
      for (int q = 0; q < 4; ++q) {
        const float2 fa = __half22float2(hpa[q]);
        acc[q * 2] = cfs * fa.x;
        acc[q * 2 + 1] = cfs * fa.y;
      }
    }
    for (int base = beg; base < end; base += 8) {
      const int e = base + g;
      const bool v = e < end;
      const int s = v ? csr_src[e] : i;
      const float cf = v ? dinv[s] * di : 0.f;
      const float4 ha = *reinterpret_cast<const float4*>(H + (size_t)s * 64 + sl * 8);
      const __half2* hpa = reinterpret_cast<const __half2*>(&ha);
#pragma unroll
      for (int q = 0; q < 4; ++q) {
        const float2 fa = __half22float2(hpa[q]);
        acc[q * 2] = fmaf(cf, fa.x, acc[q * 2]);
        acc[q * 2 + 1] = fmaf(cf, fa.y, acc[q * 2 + 1]);
      }
    }
#pragma unroll
    for (int j = 0; j < 8; ++j) {
      float a = acc[j];
      a += __shfl_xor(a, 8);
      a += __shfl_xor(a, 16);
      a += __shfl_xor(a, 32);
      acc[j] = a;
    }
    if (g == 0) {
      float* op = out + (size_t)i * 64 + sl * 8;
      const float4 b0 = *reinterpret_cast<const float4*>(bias + sl * 8);
      const float4 b1 = *reinterpret_cast<const float4*>(bias + sl * 8 + 4);
      float4 o;
      o.x = fmaxf(acc[0] + b0.x, 0.f);
      o.y = fmaxf(acc[1] + b0.y, 0.f);
      o.z = fmaxf(acc[2] + b0.z, 0.f);
      o.w = fmaxf(acc[3] + b0.w, 0.f);
      *reinterpret_cast<float4*>(op) = o;
      o.x = fmaxf(acc[4] + b1.x, 0.f);
      o.y = fmaxf(acc[5] + b1.y, 0.f);
      o.z = fmaxf(acc[6] + b1.z, 0.f);
      o.w = fmaxf(acc[7] + b1.w, 0.f);
      *reinterpret_cast<float4*>(op + 4) = o;
    }
  }
}

extern "C" void kernel_launch(void* const* d_in, const int* in_sizes, int n_in,
                              void* d_out, int out_size, void* d_ws,
                              size_t ws_size, hipStream_t stream) {
  const float* x  = (const float*)d_in[0];
  const int*   ei = (const int*)d_in[1];
  const float* W1 = (const float*)d_in[2];
  const float* b1 = (const float*)d_in[3];
  const float* W2 = (const float*)d_in[4];
  const float* b2 = (const float*)d_in[5];

  const int IN  = 128;
  const int n   = in_sizes[0] / IN;   // 100000
  const int E   = in_sizes[1] / 2;    // 3200000
  const int HID = in_sizes[2] / IN;   // 128
  const int* srcv = ei;
  const int* dstv = ei + E;
  float* out = (float*)d_out;

  const int NBKT = (n + 255) >> BSHIFT;    // buckets (391)
  const int NCHK = (E + 4095) / 4096;      // partition chunks (782)
  const int NT1  = (n + 31) / 32;          // layer-1 tiles (3125)
  const int NT2  = (n + 63) / 64;          // layer-2 tiles (1563)

  // Workspace (~90.5 MB): part[] aliases bufHp (dead until gather128 writes it).
  char* p = (char*)d_ws;
  auto take = [&](size_t bytes) {
    char* r = p;
    p += (bytes + 255) & ~(size_t)255;
    return r;
  };
  float*  dinv    = (float*)take((size_t)n * 4);
  int*    offsets = (int*)take((size_t)(n + 1) * 4);
  int*    bkthist = (int*)take(512 * 4);
  int*    bktbase = (int*)take(512 * 4);
  int*    bktcur  = (int*)take(512 * 4);
  int*    csr_src = (int*)take((size_t)E * 4);            // 12.8 MB
  __half* H16     = (__half*)take((size_t)n * 128 * 2);   // 25.6 MB (H1; later H2)
  float*  bufHp   = (float*)take((size_t)n * HID * 4);    // 51.2 MB (h' fp32)
  int*    part    = (int*)bufHp;                          // 12.8 MB alias

  // --- CSR build (no per-node global atomics) ---
  hipMemsetAsync(bkthist, 0, 512 * 4, stream);
  k_hist<<<1024, 256, 0, stream>>>(dstv, bkthist, E);
  k_bktscan<<<1, 256, 0, stream>>>(bkthist, bktbase, bktcur, offsets, n, E, NBKT);
  k_part<<<NCHK, 256, 0, stream>>>(srcv, dstv, bktcur, part, E, NBKT);
  k_csr2<<<NBKT, 256, 0, stream>>>(part, bktbase, offsets, csr_src, dinv, n);

  // --- layer 1: H1 = x@W1 (MFMA fp16, full 128 cols) ; 128-ch gather ---
  k_gemm_mfma<float, 128><<<512, 256, 0, stream>>>(x, W1, H16, n, NT1);
  k_gather128<<<25000, 256, 0, stream>>>(H16, offsets, csr_src, dinv, b1,
                                         bufHp, n);

  // --- layer 2: H2 = h'@W2 (MFMA fp16) ; 64-ch gather -> d_out ---
  k_gemm_mfma<float, 64><<<512, 256, 0, stream>>>(bufHp, W2, H16, n, NT2);
  k_gather64<<<25000, 256, 0, stream>>>(H16, offsets, csr_src, dinv, b2,
                                        out, n);
}